// Round 12
// baseline (190.630 us; speedup 1.0000x reference)
//
#include <hip/hip_runtime.h>
#include <hip/hip_bf16.h>

// GAT batch: B=32, N=512, Fin=128, Fhid=64, H=8, C=16.  fp32 I/O.
#define GB 32
#define GN 512
#define GFIN 128
#define GFH 64
#define GH 8
#define GC 16

typedef short short8 __attribute__((ext_vector_type(8)));   // 8 bf16 (MFMA A/B frag)
typedef float f32x4 __attribute__((ext_vector_type(4)));    // MFMA C/D frag

__device__ __forceinline__ ushort f2bf(float f) {
  unsigned u = __float_as_uint(f);
  return (ushort)((u + 0x7FFFu + ((u >> 16) & 1u)) >> 16);  // RNE
}
__device__ __forceinline__ unsigned pk2(float a, float b) {
  float2 f2; f2.x = a; f2.y = b;
  __hip_bfloat162 h = __float22bfloat162_rn(f2);
  union { __hip_bfloat162 h; unsigned u; } cv;
  cv.h = h;
  return cv.u;
}
__device__ __forceinline__ short8 ones8() {
  short8 o;
#pragma unroll
  for (int i = 0; i < 8; ++i) o[i] = (short)0x3F80;  // bf16 1.0
  return o;
}
__device__ __forceinline__ float fdiv_fast(float a, float b) {
  return a * __builtin_amdgcn_rcpf(b);   // 1-ulp rcp; feeds bf16
}

// ---------------------------------------------------------------------------
// K1: gemm1 standalone: V^T bf16 + exact fp32 f1/f2. grid = 1024+1
// (blk 1024: W_out -> WoT bf16 transpose). No pack — attn1 reads adj direct.
// ---------------------------------------------------------------------------
__global__ __launch_bounds__(256) void k_gemm1(
    const float* __restrict__ xg, const float* __restrict__ Wg,
    const float* __restrict__ a1g, const float* __restrict__ a2g,
    ushort* __restrict__ VTg, float* __restrict__ f1g, float* __restrict__ f2g,
    const float* __restrict__ Wog, ushort* __restrict__ WoT) {
  __shared__ ushort Wt[64][136];
  __shared__ ushort xl[128][136];
  int blk = blockIdx.x;
  int tid = threadIdx.x;

  if (blk == 1024) {                // W_out transpose+cvt: [512][16]->[16][512]
    for (int i = tid; i < 512 * GC; i += 256) {
      int k = i & 511, cc = i >> 9;
      WoT[cc * 512 + k] = f2bf(Wog[(size_t)k * GC + cc]);
    }
    return;
  }

  int bh = blk >> 2, rq = blk & 3;
  int b = bh >> 3, h = bh & 7;
  int r0 = rq * 128;
  int lane = tid & 63, w = tid >> 6;
  int c = lane & 15, q = lane >> 4;

  const float* Wh = Wg + (size_t)h * GFIN * GFH;
  for (int i = tid; i < GFIN * GFH; i += 256) {
    int f = i >> 6, j = i & 63;
    Wt[j][f] = f2bf(Wh[i]);
  }
  const float* xb = xg + ((size_t)b * GN + r0) * GFIN;
  for (int u = tid; u < 128 * 32; u += 256) {
    int row = u >> 5, c4 = u & 31;
    float4 xf = *(const float4*)&xb[(size_t)row * GFIN + c4 * 4];
    uint2 us;
    us.x = pk2(xf.x, xf.y);
    us.y = pk2(xf.z, xf.w);
    *(uint2*)&xl[row][c4 * 4] = us;
  }
  __syncthreads();

  short8 Bf[4][4];
#pragma unroll
  for (int cb = 0; cb < 4; ++cb)
#pragma unroll
    for (int kk = 0; kk < 4; ++kk)
      Bf[cb][kk] = *(const short8*)&Wt[cb * 16 + c][kk * 32 + q * 8];

  float a1v[4], a2v[4];
#pragma unroll
  for (int cb = 0; cb < 4; ++cb) {
    a1v[cb] = a1g[h * 64 + cb * 16 + c];
    a2v[cb] = a2g[h * 64 + cb * 16 + c];
  }

  f32x4 acc[2][4];
#pragma unroll
  for (int r = 0; r < 2; ++r)
#pragma unroll
    for (int cb = 0; cb < 4; ++cb) acc[r][cb] = (f32x4){0.f, 0.f, 0.f, 0.f};

#pragma unroll
  for (int kk = 0; kk < 4; ++kk) {
    short8 A0 = *(const short8*)&xl[(w * 2 + 0) * 16 + c][kk * 32 + q * 8];
    short8 A1 = *(const short8*)&xl[(w * 2 + 1) * 16 + c][kk * 32 + q * 8];
#pragma unroll
    for (int cb = 0; cb < 4; ++cb) {
      acc[0][cb] = __builtin_amdgcn_mfma_f32_16x16x32_bf16(A0, Bf[cb][kk], acc[0][cb], 0, 0, 0);
      acc[1][cb] = __builtin_amdgcn_mfma_f32_16x16x32_bf16(A1, Bf[cb][kk], acc[1][cb], 0, 0, 0);
    }
  }

  ushort* VT = VTg + (size_t)bh * GN * GFH;
  float* f1o = f1g + (size_t)bh * GN;
  float* f2o = f2g + (size_t)bh * GN;
#pragma unroll
  for (int rbi = 0; rbi < 2; ++rbi) {
    int rowb = r0 + (w * 2 + rbi) * 16 + q * 4;
    float v1[4] = {0.f, 0.f, 0.f, 0.f}, v2[4] = {0.f, 0.f, 0.f, 0.f};
#pragma unroll
    for (int cb = 0; cb < 4; ++cb) {
      f32x4 a = acc[rbi][cb];
      uint2 vs;
      vs.x = pk2(a[0], a[1]);
      vs.y = pk2(a[2], a[3]);
      *(uint2*)&VT[(size_t)(cb * 16 + c) * GN + rowb] = vs;
#pragma unroll
      for (int i = 0; i < 4; ++i) {
        v1[i] += a[i] * a1v[cb];
        v2[i] += a[i] * a2v[cb];
      }
    }
#pragma unroll
    for (int i = 0; i < 4; ++i) {
#pragma unroll
      for (int off = 1; off < 16; off <<= 1) {
        v1[i] += __shfl_xor(v1[i], off);
        v2[i] += __shfl_xor(v2[i], off);
      }
      if (c == 0) { f1o[rowb + i] = v1[i]; f2o[rowb + i] = v2[i]; }
    }
  }
}

// ---------------------------------------------------------------------------
// K2: layer-1 attention v8: reads adj DIRECTLY (int4x2/row/lane; masking via
// per-int cndmask, same VALU as byte test) — the 134 MB adj HBM read now
// overlaps MFMA/VALU instead of a serial pack pass. h==0 blocks emit the
// byte-mask for attn2 as a side product. grid 2048 = h*256 + b*8 + slice:
// XCD = slice -> all 8 heads of one adj row-slice share one XCD's L2
// (4 MB slice = L2 size); VT comes via L3 (16.8 MB, cheap).
// ---------------------------------------------------------------------------
__global__ __launch_bounds__(256, 4) void k_attn1(
    const ushort* __restrict__ VTg, const int* __restrict__ adj,
    const float* __restrict__ f1g, const float* __restrict__ f2g,
    ushort* __restrict__ xcb, unsigned char* __restrict__ maskb) {
  __shared__ ushort P[2][16][520];       // 33.3 KB double buffer
  int blk = blockIdx.x;
  int h = blk >> 8;
  int rem = blk & 255;
  int b = rem >> 3, slice = rem & 7;
  int bh = b * 8 + h;
  int r0 = slice * 64;
  int tid = threadIdx.x, lane = tid & 63, w = tid >> 6;
  int c = lane & 15, q = lane >> 4;

  const int* adjb = adj + (size_t)b * GN * GN;
  const float* f1w = f1g + (size_t)bh * GN;
  const float* f2w = f2g + (size_t)bh * GN;

  // Column factors (512 cols, 8 per lane).
  float4 fa = *(const float4*)&f2w[lane * 8];
  float4 fb = *(const float4*)&f2w[lane * 8 + 4];
  float E2[8], e2[8];
  {
    float f2v[8] = {fa.x, fa.y, fa.z, fa.w, fb.x, fb.y, fb.z, fb.w};
#pragma unroll
    for (int i = 0; i < 8; ++i) {
      E2[i] = __expf(f2v[i]);
      e2[i] = __expf(0.2f * f2v[i]);
    }
  }
  // Row factors: 64 rows, one per lane.
  float f1v = f1w[r0 + lane];
  float E1v = __expf(f1v), e1v = __expf(0.2f * f1v);

  const ushort* VT = VTg + (size_t)bh * GN * GFH + (size_t)(w * 16 + c) * GN + q * 8;
  short8 Bf[16];
#pragma unroll
  for (int kk = 0; kk < 16; ++kk) Bf[kk] = *(const short8*)&VT[kk * 32];
  const short8 ONES = ones8();

  int4 av[4][2];                         // adj ints for one 16-row tile
  // ---- load adj tile 0 ----
#pragma unroll
  for (int ri = 0; ri < 4; ++ri) {
    const int* ar = adjb + (size_t)(r0 + w + 4 * ri) * GN + lane * 8;
    av[ri][0] = *(const int4*)ar;
    av[ri][1] = *(const int4*)(ar + 4);
  }
  // ---- scores tile 0 -> P[0] (+ byte-mask for h==0) ----
#pragma unroll
  for (int ri = 0; ri < 4; ++ri) {
    float E1r = __shfl(E1v, w + 4 * ri);
    float e1r = __shfl(e1v, w + 4 * ri);
    int4 a0 = av[ri][0], a1 = av[ri][1];
    int m[8] = {a0.x, a0.y, a0.z, a0.w, a1.x, a1.y, a1.z, a1.w};
    float p[8];
#pragma unroll
    for (int i = 0; i < 8; ++i) {
      float v = fmaxf(E1r * E2[i], e1r * e2[i]);  // exp(LeakyReLU(s))
      p[i] = (m[i] > 0) ? v : 0.f;
    }
    if (h == 0) {
      unsigned mb = (unsigned)(m[0] > 0);
#pragma unroll
      for (int i = 1; i < 8; ++i) mb |= ((unsigned)(m[i] > 0)) << i;
      maskb[((size_t)b * GN + r0 + w + 4 * ri) * 64 + lane] = (unsigned char)mb;
    }
    uint4 u;
    u.x = pk2(p[0], p[1]);
    u.y = pk2(p[2], p[3]);
    u.z = pk2(p[4], p[5]);
    u.w = pk2(p[6], p[7]);
    *(uint4*)&P[0][w + 4 * ri][lane * 8] = u;
  }
  // ---- load adj tile 1 ----
#pragma unroll
  for (int ri = 0; ri < 4; ++ri) {
    const int* ar = adjb + (size_t)(r0 + 16 + w + 4 * ri) * GN + lane * 8;
    av[ri][0] = *(const int4*)ar;
    av[ri][1] = *(const int4*)(ar + 4);
  }
  __syncthreads();

#pragma unroll
  for (int t = 0; t < 4; ++t) {
    int tb = r0 + t * 16;
    const ushort (*Pc)[520] = P[t & 1];

    f32x4 acc = (f32x4){0.f, 0.f, 0.f, 0.f};
    f32x4 aL = (f32x4){0.f, 0.f, 0.f, 0.f};
#pragma unroll
    for (int kk = 0; kk < 16; ++kk) {
      short8 A = *(const short8*)&Pc[c][kk * 32 + q * 8];
      acc = __builtin_amdgcn_mfma_f32_16x16x32_bf16(A, Bf[kk], acc, 0, 0, 0);
      aL  = __builtin_amdgcn_mfma_f32_16x16x32_bf16(A, ONES, aL, 0, 0, 0);
    }

    // scores for tile t+1 (consume av) -> other buffer; overlap MFMA shadow.
    if (t < 3) {
#pragma unroll
      for (int ri = 0; ri < 4; ++ri) {
        float E1r = __shfl(E1v, (t + 1) * 16 + w + 4 * ri);
        float e1r = __shfl(e1v, (t + 1) * 16 + w + 4 * ri);
        int4 a0 = av[ri][0], a1 = av[ri][1];
        int m[8] = {a0.x, a0.y, a0.z, a0.w, a1.x, a1.y, a1.z, a1.w};
        float p[8];
#pragma unroll
        for (int i = 0; i < 8; ++i) {
          float v = fmaxf(E1r * E2[i], e1r * e2[i]);
          p[i] = (m[i] > 0) ? v : 0.f;
        }
        if (h == 0) {
          unsigned mb = (unsigned)(m[0] > 0);
#pragma unroll
          for (int i = 1; i < 8; ++i) mb |= ((unsigned)(m[i] > 0)) << i;
          maskb[((size_t)b * GN + tb + 16 + w + 4 * ri) * 64 + lane] =
              (unsigned char)mb;
        }
        uint4 u;
        u.x = pk2(p[0], p[1]);
        u.y = pk2(p[2], p[3]);
        u.z = pk2(p[4], p[5]);
        u.w = pk2(p[6], p[7]);
        *(uint4*)&P[(t + 1) & 1][w + 4 * ri][lane * 8] = u;
      }
      if (t < 2) {                       // adj ints for tile t+2, in flight
#pragma unroll
        for (int ri = 0; ri < 4; ++ri) {
          const int* ar = adjb + (size_t)(tb + 32 + w + 4 * ri) * GN + lane * 8;
          av[ri][0] = *(const int4*)ar;
          av[ri][1] = *(const int4*)(ar + 4);
        }
      }
    }

    // epilogue tile t: normalize (fast rcp) + elu + store
#pragma unroll
    for (int i = 0; i < 4; ++i) {
      int row = tb + q * 4 + i;
      float v = fdiv_fast(acc[i], fmaxf(aL[i], 1e-30f));
      v = v > 0.f ? v : __expf(v) - 1.f;            // elu
      xcb[((size_t)(b * GN + row)) * 512 + h * 64 + w * 16 + c] = f2bf(v);
    }
    __syncthreads();
  }
}

// ---------------------------------------------------------------------------
// K3: gemm2 via MFMA, A-frags straight from L2-resident xcb. grid = 256.
// ---------------------------------------------------------------------------
__global__ __launch_bounds__(256) void k_gemm2(
    const ushort* __restrict__ xcb, const ushort* __restrict__ WoT,
    const float* __restrict__ a1o, const float* __restrict__ a2o,
    ushort* __restrict__ hTg, float* __restrict__ f1bg,
    float* __restrict__ f2bg) {
  int vb = blockIdx.x;
  int b = vb >> 3, r0 = (vb & 7) * 64;
  int tid = threadIdx.x, lane = tid & 63, w = tid >> 6;
  int c = lane & 15, q = lane >> 4;

  short8 Bf[16];
#pragma unroll
  for (int kk = 0; kk < 16; ++kk)
    Bf[kk] = *(const short8*)&WoT[(size_t)c * 512 + kk * 32 + q * 8];

  const ushort* xrow = xcb + ((size_t)(b * GN + r0 + w * 16 + c)) * 512 + q * 8;
  f32x4 acc = (f32x4){0.f, 0.f, 0.f, 0.f};
#pragma unroll
  for (int kk = 0; kk < 16; ++kk) {
    short8 A = *(const short8*)&xrow[kk * 32];
    acc = __builtin_amdgcn_mfma_f32_16x16x32_bf16(A, Bf[kk], acc, 0, 0, 0);
  }

  float a1v = a1o[c], a2v = a2o[c];
  int rowb = r0 + w * 16 + q * 4;
  uint2 vs;
  vs.x = pk2(acc[0], acc[1]);
  vs.y = pk2(acc[2], acc[3]);
  *(uint2*)&hTg[((size_t)b * GC + c) * 512 + rowb] = vs;
#pragma unroll
  for (int i = 0; i < 4; ++i) {
    float v1 = acc[i] * a1v, v2 = acc[i] * a2v;
#pragma unroll
    for (int off = 1; off < 16; off <<= 1) {
      v1 += __shfl_xor(v1, off);
      v2 += __shfl_xor(v2, off);
    }
    if (c == 0) {
      f1bg[(size_t)b * GN + rowb + i] = v1;
      f2bg[(size_t)b * GN + rowb + i] = v2;
    }
  }
}

// ---------------------------------------------------------------------------
// K4: layer-2 attention. grid = 512 (b*16 + 32-row tile). Byte-mask from
// attn1's h==0 blocks; ones-MFMA L + fast-rcp epilogue.
// ---------------------------------------------------------------------------
__global__ __launch_bounds__(256) void k_attn2(
    const ushort* __restrict__ hTg, const unsigned char* __restrict__ maskb,
    const float* __restrict__ f1g, const float* __restrict__ f2g,
    float* __restrict__ outg) {
  __shared__ ushort P[32][520];
  int vb = blockIdx.x;
  int b = vb >> 4, r0 = (vb & 15) * 32;
  int tid = threadIdx.x, lane = tid & 63, w = tid >> 6;
  int c = lane & 15, q = lane >> 4;
  const short8 ONES = ones8();

  const float* f1w = f1g + (size_t)b * GN;
  const float* f2w = f2g + (size_t)b * GN;

  float4 fa = *(const float4*)&f2w[lane * 8];
  float4 fb = *(const float4*)&f2w[lane * 8 + 4];
  float E2[8], e2[8];
  {
    float f2v[8] = {fa.x, fa.y, fa.z, fa.w, fb.x, fb.y, fb.z, fb.w};
#pragma unroll
    for (int i = 0; i < 8; ++i) {
      E2[i] = __expf(f2v[i]);
      e2[i] = __expf(0.2f * f2v[i]);
    }
  }
  float f1v = 0.f;
  if (lane < 8) f1v = f1w[r0 + w * 8 + lane];
  float E1v = __expf(f1v), e1v = __expf(0.2f * f1v);

  unsigned mword[8];
#pragma unroll
  for (int ri = 0; ri < 8; ++ri)
    mword[ri] = maskb[((size_t)b * GN + r0 + w * 8 + ri) * 64 + lane];
#pragma unroll
  for (int ri = 0; ri < 8; ++ri) {
    float E1r = __shfl(E1v, ri);
    float e1r = __shfl(e1v, ri);
    unsigned mb = mword[ri];
    float p[8];
#pragma unroll
    for (int i = 0; i < 8; ++i) {
      float v = fmaxf(E1r * E2[i], e1r * e2[i]);
      p[i] = ((mb >> i) & 1u) ? v : 0.f;
    }
    uint4 u;
    u.x = pk2(p[0], p[1]);
    u.y = pk2(p[2], p[3]);
    u.z = pk2(p[4], p[5]);
    u.w = pk2(p[6], p[7]);
    *(uint4*)&P[w * 8 + ri][lane * 8] = u;
  }
  __syncthreads();

  if (w < 2) {                     // two 16-row MFMA tiles
    short8 Bf[16];
#pragma unroll
    for (int kk = 0; kk < 16; ++kk)
      Bf[kk] = *(const short8*)&hTg[((size_t)b * GC + c) * 512 + kk * 32 + q * 8];
    f32x4 acc = (f32x4){0.f, 0.f, 0.f, 0.f};
    f32x4 aL = (f32x4){0.f, 0.f, 0.f, 0.f};
#pragma unroll
    for (int kk = 0; kk < 16; ++kk) {
      short8 A = *(const short8*)&P[w * 16 + c][kk * 32 + q * 8];
      acc = __builtin_amdgcn_mfma_f32_16x16x32_bf16(A, Bf[kk], acc, 0, 0, 0);
      aL  = __builtin_amdgcn_mfma_f32_16x16x32_bf16(A, ONES, aL, 0, 0, 0);
    }
#pragma unroll
    for (int i = 0; i < 4; ++i) {
      int row = r0 + w * 16 + q * 4 + i;
      outg[((size_t)(b * GN + row)) * GC + c] =
          fdiv_fast(acc[i], fmaxf(aL[i], 1e-30f));
    }
  }
}

// ---------------------------------------------------------------------------
extern "C" void kernel_launch(void* const* d_in, const int* in_sizes, int n_in,
                              void* d_out, int out_size, void* d_ws, size_t ws_size,
                              hipStream_t stream) {
  (void)in_sizes; (void)n_in; (void)out_size;
  const float* x   = (const float*)d_in[0];
  const int*   adj = (const int*)d_in[1];
  const float* Whd = (const float*)d_in[2];
  const float* a1h = (const float*)d_in[3];
  const float* a2h = (const float*)d_in[4];
  const float* Wo  = (const float*)d_in[5];
  const float* a1o = (const float*)d_in[6];
  const float* a2o = (const float*)d_in[7];

  size_t off = 0;
  char* base = (char*)d_ws;
  unsigned char* mb = (unsigned char*)(base + off); off += (size_t)GB * GN * 64; // 1 MB
  ushort* VT   = (ushort*)(base + off);   off += (size_t)GB * GH * GN * GFH * 2; // 16.8 MB
  ushort* xcb  = (ushort*)(base + off);   off += (size_t)GB * GN * 512 * 2;      // 16.8 MB
  ushort* WoT  = (ushort*)(base + off);   off += (size_t)GC * 512 * 2;           // 16 KB
  ushort* hT   = (ushort*)(base + off);   off += (size_t)GB * GC * GN * 2;       // 0.5 MB
  float* f1    = (float*)(base + off);    off += (size_t)GB * GH * GN * 4;       // 0.5 MB
  float* f2    = (float*)(base + off);    off += (size_t)GB * GH * GN * 4;       // 0.5 MB
  float* f1b   = (float*)(base + off);    off += (size_t)GB * GN * 4;
  float* f2b   = (float*)(base + off);    off += (size_t)GB * GN * 4;

  if (ws_size < off) return;

  hipLaunchKernelGGL(k_gemm1, dim3(1025), dim3(256), 0, stream,
                     x, Whd, a1h, a2h, VT, f1, f2, Wo, WoT);
  hipLaunchKernelGGL(k_attn1, dim3(2048), dim3(256), 0, stream,
                     VT, adj, f1, f2, xcb, mb);
  hipLaunchKernelGGL(k_gemm2, dim3(256), dim3(256), 0, stream,
                     xcb, WoT, a1o, a2o, hT, f1b, f2b);
  hipLaunchKernelGGL(k_attn2, dim3(512), dim3(256), 0, stream,
                     hT, mb, f1b, f2b, (float*)d_out);
}

// Round 13
// 149.728 us; speedup vs baseline: 1.2732x; 1.2732x over previous
//
#include <hip/hip_runtime.h>
#include <hip/hip_bf16.h>

// GAT batch: B=32, N=512, Fin=128, Fhid=64, H=8, C=16.  fp32 I/O.
// R13 = exact revert to R11 (best known: 151.26 us). R12's direct-adj read
// falsified (L3 can't hold 8x adj re-reads; FETCH 182 MB, attn1 90 us).
#define GB 32
#define GN 512
#define GFIN 128
#define GFH 64
#define GH 8
#define GC 16

typedef short short8 __attribute__((ext_vector_type(8)));   // 8 bf16 (MFMA A/B frag)
typedef float f32x4 __attribute__((ext_vector_type(4)));    // MFMA C/D frag

__device__ __forceinline__ ushort f2bf(float f) {
  unsigned u = __float_as_uint(f);
  return (ushort)((u + 0x7FFFu + ((u >> 16) & 1u)) >> 16);  // RNE
}
__device__ __forceinline__ unsigned pk2(float a, float b) {
  float2 f2; f2.x = a; f2.y = b;
  __hip_bfloat162 h = __float22bfloat162_rn(f2);
  union { __hip_bfloat162 h; unsigned u; } cv;
  cv.h = h;
  return cv.u;
}
__device__ __forceinline__ short8 ones8() {
  short8 o;
#pragma unroll
  for (int i = 0; i < 8; ++i) o[i] = (short)0x3F80;  // bf16 1.0
  return o;
}
// Fast a/b: v_rcp_f32 (1 ulp) + mul — result feeds bf16, noise-level error.
__device__ __forceinline__ float fdiv_fast(float a, float b) {
  return a * __builtin_amdgcn_rcpf(b);
}

// ---------------------------------------------------------------------------
// K1: blocks [0,1024): gemm1 (V^T bf16 + exact fp32 f1/f2). Blocks
// [1024,5120): adj bit-pack (ILP-8; HBM-bound 134 MB read, done ONCE).
// Block 5120: W_out -> WoT bf16.
// ---------------------------------------------------------------------------
__global__ __launch_bounds__(256) void k_pack_gemm1(
    const int* __restrict__ adj, unsigned* __restrict__ mw,
    const float* __restrict__ xg, const float* __restrict__ Wg,
    const float* __restrict__ a1g, const float* __restrict__ a2g,
    ushort* __restrict__ VTg, float* __restrict__ f1g, float* __restrict__ f2g,
    const float* __restrict__ Wog, ushort* __restrict__ WoT) {
  __shared__ ushort Wt[64][136];
  __shared__ ushort xl[128][136];
  int blk = blockIdx.x;
  int tid = threadIdx.x;

  if (blk == 5120) {
    for (int i = tid; i < 512 * GC; i += 256) {
      int k = i & 511, cc = i >> 9;
      WoT[cc * 512 + k] = f2bf(Wog[(size_t)k * GC + cc]);
    }
    return;
  }
  if (blk >= 1024) {
    int pblk = blk - 1024;
    int lane = tid & 63;
    int base = pblk * 2048 + tid;
    int v[8];
#pragma unroll
    for (int it = 0; it < 8; ++it) v[it] = adj[(size_t)base + it * 256];
#pragma unroll
    for (int it = 0; it < 8; ++it) {
      unsigned long long m = __ballot(v[it] > 0);
      int idx = base + it * 256;
      if (lane == 0)       mw[idx >> 5] = (unsigned)m;
      else if (lane == 32) mw[idx >> 5] = (unsigned)(m >> 32);
    }
    return;
  }

  int bh = blk >> 2, rq = blk & 3;
  int b = bh >> 3, h = bh & 7;
  int r0 = rq * 128;
  int lane = tid & 63, w = tid >> 6;
  int c = lane & 15, q = lane >> 4;

  const float* Wh = Wg + (size_t)h * GFIN * GFH;
  for (int i = tid; i < GFIN * GFH; i += 256) {
    int f = i >> 6, j = i & 63;
    Wt[j][f] = f2bf(Wh[i]);
  }
  const float* xb = xg + ((size_t)b * GN + r0) * GFIN;
  for (int u = tid; u < 128 * 32; u += 256) {
    int row = u >> 5, c4 = u & 31;
    float4 xf = *(const float4*)&xb[(size_t)row * GFIN + c4 * 4];
    uint2 us;
    us.x = pk2(xf.x, xf.y);
    us.y = pk2(xf.z, xf.w);
    *(uint2*)&xl[row][c4 * 4] = us;
  }
  __syncthreads();

  short8 Bf[4][4];
#pragma unroll
  for (int cb = 0; cb < 4; ++cb)
#pragma unroll
    for (int kk = 0; kk < 4; ++kk)
      Bf[cb][kk] = *(const short8*)&Wt[cb * 16 + c][kk * 32 + q * 8];

  float a1v[4], a2v[4];
#pragma unroll
  for (int cb = 0; cb < 4; ++cb) {
    a1v[cb] = a1g[h * 64 + cb * 16 + c];
    a2v[cb] = a2g[h * 64 + cb * 16 + c];
  }

  f32x4 acc[2][4];
#pragma unroll
  for (int r = 0; r < 2; ++r)
#pragma unroll
    for (int cb = 0; cb < 4; ++cb) acc[r][cb] = (f32x4){0.f, 0.f, 0.f, 0.f};

#pragma unroll
  for (int kk = 0; kk < 4; ++kk) {
    short8 A0 = *(const short8*)&xl[(w * 2 + 0) * 16 + c][kk * 32 + q * 8];
    short8 A1 = *(const short8*)&xl[(w * 2 + 1) * 16 + c][kk * 32 + q * 8];
#pragma unroll
    for (int cb = 0; cb < 4; ++cb) {
      acc[0][cb] = __builtin_amdgcn_mfma_f32_16x16x32_bf16(A0, Bf[cb][kk], acc[0][cb], 0, 0, 0);
      acc[1][cb] = __builtin_amdgcn_mfma_f32_16x16x32_bf16(A1, Bf[cb][kk], acc[1][cb], 0, 0, 0);
    }
  }

  ushort* VT = VTg + (size_t)bh * GN * GFH;
  float* f1o = f1g + (size_t)bh * GN;
  float* f2o = f2g + (size_t)bh * GN;
#pragma unroll
  for (int rbi = 0; rbi < 2; ++rbi) {
    int rowb = r0 + (w * 2 + rbi) * 16 + q * 4;
    float v1[4] = {0.f, 0.f, 0.f, 0.f}, v2[4] = {0.f, 0.f, 0.f, 0.f};
#pragma unroll
    for (int cb = 0; cb < 4; ++cb) {
      f32x4 a = acc[rbi][cb];
      uint2 vs;
      vs.x = pk2(a[0], a[1]);
      vs.y = pk2(a[2], a[3]);
      *(uint2*)&VT[(size_t)(cb * 16 + c) * GN + rowb] = vs;
#pragma unroll
      for (int i = 0; i < 4; ++i) {
        v1[i] += a[i] * a1v[cb];
        v2[i] += a[i] * a2v[cb];
      }
    }
#pragma unroll
    for (int i = 0; i < 4; ++i) {
#pragma unroll
      for (int off = 1; off < 16; off <<= 1) {
        v1[i] += __shfl_xor(v1[i], off);
        v2[i] += __shfl_xor(v2[i], off);
      }
      if (c == 0) { f1o[rowb + i] = v1[i]; f2o[rowb + i] = v2[i]; }
    }
  }
}

// ---------------------------------------------------------------------------
// K2: layer-1 attention v7: 16-row dbuf P (33.3 KB), 4 blocks/CU, ones-MFMA
// row sums (free in idle MFMA pipe), fast-rcp epilogue, mask prefetch.
// grid 2048 = slice*256 + bh.
// ---------------------------------------------------------------------------
__global__ __launch_bounds__(256, 4) void k_attn1(
    const ushort* __restrict__ VTg, const unsigned* __restrict__ mwg,
    const float* __restrict__ f1g, const float* __restrict__ f2g,
    ushort* __restrict__ xcb) {
  __shared__ ushort P[2][16][520];       // 33.3 KB double buffer
  int blk = blockIdx.x;
  int bh = blk & 255, slice = blk >> 8;
  int b = bh >> 3, h = bh & 7;
  int r0 = slice * 64;
  int tid = threadIdx.x, lane = tid & 63, w = tid >> 6;
  int c = lane & 15, q = lane >> 4;

  const unsigned* mwb = mwg + (size_t)b * GN * 16;
  const float* f1w = f1g + (size_t)bh * GN;
  const float* f2w = f2g + (size_t)bh * GN;

  float4 fa = *(const float4*)&f2w[lane * 8];
  float4 fb = *(const float4*)&f2w[lane * 8 + 4];
  float E2[8], e2[8];
  {
    float f2v[8] = {fa.x, fa.y, fa.z, fa.w, fb.x, fb.y, fb.z, fb.w};
#pragma unroll
    for (int i = 0; i < 8; ++i) {
      E2[i] = __expf(f2v[i]);
      e2[i] = __expf(0.2f * f2v[i]);
    }
  }
  float f1v = f1w[r0 + lane];
  float E1v = __expf(f1v), e1v = __expf(0.2f * f1v);

  const ushort* VT = VTg + (size_t)bh * GN * GFH + (size_t)(w * 16 + c) * GN + q * 8;
  short8 Bf[16];
#pragma unroll
  for (int kk = 0; kk < 16; ++kk) Bf[kk] = *(const short8*)&VT[kk * 32];
  const short8 ONES = ones8();

  unsigned mn[4];
#pragma unroll
  for (int ri = 0; ri < 4; ++ri)
    mn[ri] = mwb[(size_t)(r0 + w + 4 * ri) * 16 + (lane >> 2)];
#pragma unroll
  for (int ri = 0; ri < 4; ++ri) {
    float E1r = __shfl(E1v, w + 4 * ri);
    float e1r = __shfl(e1v, w + 4 * ri);
    unsigned mb = (mn[ri] >> (8 * (lane & 3))) & 0xffu;
    float p[8];
#pragma unroll
    for (int i = 0; i < 8; ++i) {
      float v = fmaxf(E1r * E2[i], e1r * e2[i]);  // exp(LeakyReLU(s))
      p[i] = ((mb >> i) & 1u) ? v : 0.f;
    }
    uint4 u;
    u.x = pk2(p[0], p[1]);
    u.y = pk2(p[2], p[3]);
    u.z = pk2(p[4], p[5]);
    u.w = pk2(p[6], p[7]);
    *(uint4*)&P[0][w + 4 * ri][lane * 8] = u;
  }
#pragma unroll
  for (int ri = 0; ri < 4; ++ri)
    mn[ri] = mwb[(size_t)(r0 + 16 + w + 4 * ri) * 16 + (lane >> 2)];
  __syncthreads();

#pragma unroll
  for (int t = 0; t < 4; ++t) {
    int tb = r0 + t * 16;
    const ushort (*Pc)[520] = P[t & 1];

    f32x4 acc = (f32x4){0.f, 0.f, 0.f, 0.f};
    f32x4 aL = (f32x4){0.f, 0.f, 0.f, 0.f};
#pragma unroll
    for (int kk = 0; kk < 16; ++kk) {
      short8 A = *(const short8*)&Pc[c][kk * 32 + q * 8];
      acc = __builtin_amdgcn_mfma_f32_16x16x32_bf16(A, Bf[kk], acc, 0, 0, 0);
      aL  = __builtin_amdgcn_mfma_f32_16x16x32_bf16(A, ONES, aL, 0, 0, 0);
    }

    if (t < 3) {
#pragma unroll
      for (int ri = 0; ri < 4; ++ri) {
        float E1r = __shfl(E1v, (t + 1) * 16 + w + 4 * ri);
        float e1r = __shfl(e1v, (t + 1) * 16 + w + 4 * ri);
        unsigned mb = (mn[ri] >> (8 * (lane & 3))) & 0xffu;
        float p[8];
#pragma unroll
        for (int i = 0; i < 8; ++i) {
          float v = fmaxf(E1r * E2[i], e1r * e2[i]);
          p[i] = ((mb >> i) & 1u) ? v : 0.f;
        }
        uint4 u;
        u.x = pk2(p[0], p[1]);
        u.y = pk2(p[2], p[3]);
        u.z = pk2(p[4], p[5]);
        u.w = pk2(p[6], p[7]);
        *(uint4*)&P[(t + 1) & 1][w + 4 * ri][lane * 8] = u;
      }
      if (t < 2) {
#pragma unroll
        for (int ri = 0; ri < 4; ++ri)
          mn[ri] = mwb[(size_t)(tb + 32 + w + 4 * ri) * 16 + (lane >> 2)];
      }
    }

#pragma unroll
    for (int i = 0; i < 4; ++i) {
      int row = tb + q * 4 + i;
      float v = fdiv_fast(acc[i], fmaxf(aL[i], 1e-30f));
      v = v > 0.f ? v : __expf(v) - 1.f;            // elu
      xcb[((size_t)(b * GN + row)) * 512 + h * 64 + w * 16 + c] = f2bf(v);
    }
    __syncthreads();
  }
}

// ---------------------------------------------------------------------------
// K3: gemm2 via MFMA, A-frags straight from L2-resident xcb. grid = 256.
// ---------------------------------------------------------------------------
__global__ __launch_bounds__(256) void k_gemm2(
    const ushort* __restrict__ xcb, const ushort* __restrict__ WoT,
    const float* __restrict__ a1o, const float* __restrict__ a2o,
    ushort* __restrict__ hTg, float* __restrict__ f1bg,
    float* __restrict__ f2bg) {
  int vb = blockIdx.x;
  int b = vb >> 3, r0 = (vb & 7) * 64;
  int tid = threadIdx.x, lane = tid & 63, w = tid >> 6;
  int c = lane & 15, q = lane >> 4;

  short8 Bf[16];
#pragma unroll
  for (int kk = 0; kk < 16; ++kk)
    Bf[kk] = *(const short8*)&WoT[(size_t)c * 512 + kk * 32 + q * 8];

  const ushort* xrow = xcb + ((size_t)(b * GN + r0 + w * 16 + c)) * 512 + q * 8;
  f32x4 acc = (f32x4){0.f, 0.f, 0.f, 0.f};
#pragma unroll
  for (int kk = 0; kk < 16; ++kk) {
    short8 A = *(const short8*)&xrow[kk * 32];
    acc = __builtin_amdgcn_mfma_f32_16x16x32_bf16(A, Bf[kk], acc, 0, 0, 0);
  }

  float a1v = a1o[c], a2v = a2o[c];
  int rowb = r0 + w * 16 + q * 4;
  uint2 vs;
  vs.x = pk2(acc[0], acc[1]);
  vs.y = pk2(acc[2], acc[3]);
  *(uint2*)&hTg[((size_t)b * GC + c) * 512 + rowb] = vs;
#pragma unroll
  for (int i = 0; i < 4; ++i) {
    float v1 = acc[i] * a1v, v2 = acc[i] * a2v;
#pragma unroll
    for (int off = 1; off < 16; off <<= 1) {
      v1 += __shfl_xor(v1, off);
      v2 += __shfl_xor(v2, off);
    }
    if (c == 0) {
      f1bg[(size_t)b * GN + rowb + i] = v1;
      f2bg[(size_t)b * GN + rowb + i] = v2;
    }
  }
}

// ---------------------------------------------------------------------------
// K4: layer-2 attention. grid = 512 (b*16 + 32-row tile). ones-MFMA L +
// fast-rcp epilogue.
// ---------------------------------------------------------------------------
__global__ __launch_bounds__(256) void k_attn2(
    const ushort* __restrict__ hTg, const unsigned* __restrict__ mwg,
    const float* __restrict__ f1g, const float* __restrict__ f2g,
    float* __restrict__ outg) {
  __shared__ ushort P[32][520];
  int vb = blockIdx.x;
  int b = vb >> 4, r0 = (vb & 15) * 32;
  int tid = threadIdx.x, lane = tid & 63, w = tid >> 6;
  int c = lane & 15, q = lane >> 4;
  const short8 ONES = ones8();

  const unsigned* mwb = mwg + (size_t)b * GN * 16;
  const float* f1w = f1g + (size_t)b * GN;
  const float* f2w = f2g + (size_t)b * GN;

  float4 fa = *(const float4*)&f2w[lane * 8];
  float4 fb = *(const float4*)&f2w[lane * 8 + 4];
  float E2[8], e2[8];
  {
    float f2v[8] = {fa.x, fa.y, fa.z, fa.w, fb.x, fb.y, fb.z, fb.w};
#pragma unroll
    for (int i = 0; i < 8; ++i) {
      E2[i] = __expf(f2v[i]);
      e2[i] = __expf(0.2f * f2v[i]);
    }
  }
  float f1v = 0.f;
  if (lane < 8) f1v = f1w[r0 + w * 8 + lane];
  float E1v = __expf(f1v), e1v = __expf(0.2f * f1v);

  unsigned mword[8];
#pragma unroll
  for (int ri = 0; ri < 8; ++ri)
    mword[ri] = mwb[(size_t)(r0 + w * 8 + ri) * 16 + (lane >> 2)];
#pragma unroll
  for (int ri = 0; ri < 8; ++ri) {
    float E1r = __shfl(E1v, ri);
    float e1r = __shfl(e1v, ri);
    unsigned mb = (mword[ri] >> (8 * (lane & 3))) & 0xffu;
    float p[8];
#pragma unroll
    for (int i = 0; i < 8; ++i) {
      float v = fmaxf(E1r * E2[i], e1r * e2[i]);
      p[i] = ((mb >> i) & 1u) ? v : 0.f;
    }
    uint4 u;
    u.x = pk2(p[0], p[1]);
    u.y = pk2(p[2], p[3]);
    u.z = pk2(p[4], p[5]);
    u.w = pk2(p[6], p[7]);
    *(uint4*)&P[w * 8 + ri][lane * 8] = u;
  }
  __syncthreads();

  if (w < 2) {                     // two 16-row MFMA tiles
    short8 Bf[16];
#pragma unroll
    for (int kk = 0; kk < 16; ++kk)
      Bf[kk] = *(const short8*)&hTg[((size_t)b * GC + c) * 512 + kk * 32 + q * 8];
    f32x4 acc = (f32x4){0.f, 0.f, 0.f, 0.f};
    f32x4 aL = (f32x4){0.f, 0.f, 0.f, 0.f};
#pragma unroll
    for (int kk = 0; kk < 16; ++kk) {
      short8 A = *(const short8*)&P[w * 16 + c][kk * 32 + q * 8];
      acc = __builtin_amdgcn_mfma_f32_16x16x32_bf16(A, Bf[kk], acc, 0, 0, 0);
      aL  = __builtin_amdgcn_mfma_f32_16x16x32_bf16(A, ONES, aL, 0, 0, 0);
    }
#pragma unroll
    for (int i = 0; i < 4; ++i) {
      int row = r0 + w * 16 + q * 4 + i;
      outg[((size_t)(b * GN + row)) * GC + c] =
          fdiv_fast(acc[i], fmaxf(aL[i], 1e-30f));
    }
  }
}

// ---------------------------------------------------------------------------
extern "C" void kernel_launch(void* const* d_in, const int* in_sizes, int n_in,
                              void* d_out, int out_size, void* d_ws, size_t ws_size,
                              hipStream_t stream) {
  (void)in_sizes; (void)n_in; (void)out_size;
  const float* x   = (const float*)d_in[0];
  const int*   adj = (const int*)d_in[1];
  const float* Whd = (const float*)d_in[2];
  const float* a1h = (const float*)d_in[3];
  const float* a2h = (const float*)d_in[4];
  const float* Wo  = (const float*)d_in[5];
  const float* a1o = (const float*)d_in[6];
  const float* a2o = (const float*)d_in[7];

  size_t off = 0;
  char* base = (char*)d_ws;
  unsigned* mw = (unsigned*)(base + off); off += (size_t)GB * GN * 16 * 4;       // 1 MB
  ushort* VT   = (ushort*)(base + off);   off += (size_t)GB * GH * GN * GFH * 2; // 16.8 MB
  ushort* xcb  = (ushort*)(base + off);   off += (size_t)GB * GN * 512 * 2;      // 16.8 MB
  ushort* WoT  = (ushort*)(base + off);   off += (size_t)GC * 512 * 2;           // 16 KB
  ushort* hT   = (ushort*)(base + off);   off += (size_t)GB * GC * GN * 2;       // 0.5 MB
  float* f1    = (float*)(base + off);    off += (size_t)GB * GH * GN * 4;       // 0.5 MB
  float* f2    = (float*)(base + off);    off += (size_t)GB * GH * GN * 4;       // 0.5 MB
  float* f1b   = (float*)(base + off);    off += (size_t)GB * GN * 4;
  float* f2b   = (float*)(base + off);    off += (size_t)GB * GN * 4;

  if (ws_size < off) return;

  hipLaunchKernelGGL(k_pack_gemm1, dim3(5121), dim3(256), 0, stream,
                     adj, mw, x, Whd, a1h, a2h, VT, f1, f2, Wo, WoT);
  hipLaunchKernelGGL(k_attn1, dim3(2048), dim3(256), 0, stream,
                     VT, mw, f1, f2, xcb);
  hipLaunchKernelGGL(k_gemm2, dim3(256), dim3(256), 0, stream,
                     xcb, WoT, a1o, a2o, hT, f1b, f2b);
  hipLaunchKernelGGL(k_attn2, dim3(512), dim3(256), 0, stream,
                     hT, mw, f1b, f2b, (float*)d_out);
}